// Round 2
// 626.834 us; speedup vs baseline: 1.0151x; 1.0151x over previous
//
#include <hip/hip_runtime.h>
#include <math.h>

#define D_ 1024
#define THREE_D 3072
#define B_ 32
#define T_ 2048

typedef float floatx4 __attribute__((ext_vector_type(4)));

// ---------------------------------------------------------------------------
// K1: LayerNorm over concat([raw_g, spec_g, rel_g]) per batch.
// Writes normalized result TRANSPOSED: gnT[k*32 + b]. Also zeroes pre_alpha.
// ---------------------------------------------------------------------------
__global__ __launch_bounds__(256) void ln_kernel(
    const float* __restrict__ raw_g, const float* __restrict__ spec_g,
    const float* __restrict__ rel_g, const float* __restrict__ gamma,
    const float* __restrict__ beta, float* __restrict__ gnT,
    float* __restrict__ pre_alpha) {
  const int b = blockIdx.x;
  const int tid = threadIdx.x;
  __shared__ float sg[THREE_D];
  __shared__ float red[8];
  __shared__ float stats[2];

  if (tid == 0) pre_alpha[b] = 0.f;

  float s = 0.f, s2 = 0.f;
#pragma unroll
  for (int i = 0; i < 12; ++i) {
    int k = i * 256 + tid;
    float v;
    if (k < 1024)       v = raw_g[b * 1024 + k];
    else if (k < 2048)  v = spec_g[b * 1024 + (k - 1024)];
    else                v = rel_g[b * 1024 + (k - 2048)];
    sg[k] = v;
    s += v;
    s2 += v * v;
  }
#pragma unroll
  for (int off = 32; off; off >>= 1) {
    s  += __shfl_down(s, off, 64);
    s2 += __shfl_down(s2, off, 64);
  }
  const int wv = tid >> 6;
  if ((tid & 63) == 0) { red[wv] = s; red[4 + wv] = s2; }
  __syncthreads();
  if (tid == 0) {
    float ts  = red[0] + red[1] + red[2] + red[3];
    float ts2 = red[4] + red[5] + red[6] + red[7];
    float mu  = ts * (1.0f / THREE_D);
    float var = ts2 * (1.0f / THREE_D) - mu * mu;
    stats[0] = mu;
    stats[1] = rsqrtf(var + 1e-5f);
  }
  __syncthreads();
  const float mu = stats[0], rstd = stats[1];
#pragma unroll
  for (int i = 0; i < 12; ++i) {
    int k = i * 256 + tid;
    gnT[k * 32 + b] = (sg[k] - mu) * rstd * gamma[k] + beta[k];
  }
}

// ---------------------------------------------------------------------------
// K2: partial GEMM  h_pre[b][j] = sum_k gnT[k][b] * w1[k][j]
// Grid (16 jt, 16 by), 512 threads = 8 waves (2 waves/SIMD on 256 blocks).
// Wave w: khalf = w>>1 picks one of 4 48-wide k slices of this block's
// 192-k range; bhalf = w&1 picks 16 of the 32 batches (4 float4 accs).
// gnT tile (192x32 = 24 KB) staged in LDS; all 48 w1 values prefetched
// into registers (independent loads in flight). w1 read once from HBM.
// partials layout: [slice' = kslice*2+bhalf][16 b][1024 j] f32 (8 MB).
// ---------------------------------------------------------------------------
__global__ __launch_bounds__(512) void gate_gemm(
    const float* __restrict__ gnT, const float* __restrict__ w1,
    float* __restrict__ partials) {
  const int tid   = threadIdx.x;
  const int lane  = tid & 63;
  const int wvid  = tid >> 6;        // 0..7
  const int khalf = wvid >> 1;       // 0..3
  const int bhalf = wvid & 1;        // 0..1
  const int jt = blockIdx.x;         // 0..15
  const int by = blockIdx.y;         // 0..15
  const int j  = jt * 64 + lane;
  const int kslice = by * 4 + khalf; // 0..63, 48 k each

  __shared__ float sg[192 * 32];     // 24 KB: gnT rows [by*192, by*192+192)
  const float* gsrc = gnT + by * 192 * 32;
#pragma unroll
  for (int i = 0; i < 12; ++i) sg[i * 512 + tid] = gsrc[i * 512 + tid];
  __syncthreads();

  // prefetch the 48 w1 values (coalesced 256B/wave each, all independent)
  const float* wrow = w1 + (size_t)kslice * 48 * D_ + j;
  float w[48];
#pragma unroll
  for (int kk = 0; kk < 48; ++kk) w[kk] = wrow[(size_t)kk * D_];

  float4 acc[4];
#pragma unroll
  for (int i = 0; i < 4; ++i) acc[i] = make_float4(0.f, 0.f, 0.f, 0.f);

  const float4* gp = (const float4*)(sg + (khalf * 48) * 32 + bhalf * 16);
#pragma unroll
  for (int kk = 0; kk < 48; ++kk) {
    const float4* g = gp + kk * 8;   // 32 floats per k row
    const float wv_ = w[kk];
#pragma unroll
    for (int i = 0; i < 4; ++i) {
      float4 gv = g[i];              // wave-uniform -> LDS broadcast, free
      acc[i].x = fmaf(gv.x, wv_, acc[i].x);
      acc[i].y = fmaf(gv.y, wv_, acc[i].y);
      acc[i].z = fmaf(gv.z, wv_, acc[i].z);
      acc[i].w = fmaf(gv.w, wv_, acc[i].w);
    }
  }

  float* base = partials + ((size_t)(kslice * 2 + bhalf) * 16) * D_ + j;
#pragma unroll
  for (int i = 0; i < 4; ++i) {
    base[(4 * i + 0) * D_] = acc[i].x;   // coalesced per b-row
    base[(4 * i + 1) * D_] = acc[i].y;
    base[(4 * i + 2) * D_] = acc[i].z;
    base[(4 * i + 3) * D_] = acc[i].w;
  }
}

// ---------------------------------------------------------------------------
// K3: reduce 64 k-slices, +b1, exact GELU, dot with w2 -> atomicAdd into
// pre_alpha[b]. Grid (4 jc, 32 b) = 128 blocks, 256 threads, 1 j/thread.
// ---------------------------------------------------------------------------
__global__ __launch_bounds__(256) void gate_finish(
    const float* __restrict__ partials, const float* __restrict__ b1,
    const float* __restrict__ w2, float* __restrict__ pre_alpha) {
  const int jc  = blockIdx.x;        // 0..3
  const int b   = blockIdx.y;        // 0..31
  const int tid = threadIdx.x;
  const int j   = jc * 256 + tid;
  const int bh  = b >> 4, br = b & 15;

  const float* p = partials + ((size_t)bh * 16 + br) * D_ + j;
  float s = b1[j];
#pragma unroll 8
  for (int sl = 0; sl < 64; ++sl)
    s += p[(size_t)sl * 32768];      // (sl*2)*16*1024, coalesced across tid
  // exact GELU
  float h = 0.5f * s * (1.0f + erff(s * 0.7071067811865476f));
  float c = h * w2[j];

#pragma unroll
  for (int off = 32; off; off >>= 1) c += __shfl_down(c, off, 64);
  __shared__ float red[4];
  if ((tid & 63) == 0) red[tid >> 6] = c;
  __syncthreads();
  if (tid == 0)
    atomicAdd(&pre_alpha[b], red[0] + red[1] + red[2] + red[3]);
}

// ---------------------------------------------------------------------------
// K3.5: alpha[b] = sigmoid(pre_alpha[b] + b2)
// ---------------------------------------------------------------------------
__global__ __launch_bounds__(64) void alphify(
    const float* __restrict__ pre_alpha, const float* __restrict__ b2,
    float* __restrict__ alpha_out) {
  const int tid = threadIdx.x;
  if (tid < B_) {
    float t = pre_alpha[tid] + b2[0];
    alpha_out[tid] = 1.0f / (1.0f + expf(-t));
  }
}

// ---------------------------------------------------------------------------
// K4: main_repr = raw_residual + alpha[b] * rel_residual  (memory-bound).
// Grid (512, B). Each thread: 4 float4 pairs (8 loads in flight), NT stores
// so the 268 MB write stream doesn't evict the L3-resident read stream.
// ---------------------------------------------------------------------------
__global__ __launch_bounds__(256) void fuse_kernel(
    const float4* __restrict__ raw, const float4* __restrict__ rel,
    const float* __restrict__ alpha, float* __restrict__ out) {
  const int b = blockIdx.y;
  const float a = alpha[b];                       // block-uniform
  const size_t f4_per_b = (size_t)T_ * D_ / 4;    // 524288
  const size_t base = (size_t)b * f4_per_b + (size_t)blockIdx.x * 1024 + threadIdx.x;

  float4 r0 = raw[base +   0], r1 = raw[base + 256],
         r2 = raw[base + 512], r3 = raw[base + 768];
  float4 e0 = rel[base +   0], e1 = rel[base + 256],
         e2 = rel[base + 512], e3 = rel[base + 768];

  floatx4 o0, o1, o2, o3;
  o0.x = fmaf(a, e0.x, r0.x); o0.y = fmaf(a, e0.y, r0.y);
  o0.z = fmaf(a, e0.z, r0.z); o0.w = fmaf(a, e0.w, r0.w);
  o1.x = fmaf(a, e1.x, r1.x); o1.y = fmaf(a, e1.y, r1.y);
  o1.z = fmaf(a, e1.z, r1.z); o1.w = fmaf(a, e1.w, r1.w);
  o2.x = fmaf(a, e2.x, r2.x); o2.y = fmaf(a, e2.y, r2.y);
  o2.z = fmaf(a, e2.z, r2.z); o2.w = fmaf(a, e2.w, r2.w);
  o3.x = fmaf(a, e3.x, r3.x); o3.y = fmaf(a, e3.y, r3.y);
  o3.z = fmaf(a, e3.z, r3.z); o3.w = fmaf(a, e3.w, r3.w);

  floatx4* o = reinterpret_cast<floatx4*>(out) + base;
  __builtin_nontemporal_store(o0, o +   0);
  __builtin_nontemporal_store(o1, o + 256);
  __builtin_nontemporal_store(o2, o + 512);
  __builtin_nontemporal_store(o3, o + 768);
}

extern "C" void kernel_launch(void* const* d_in, const int* in_sizes, int n_in,
                              void* d_out, int out_size, void* d_ws, size_t ws_size,
                              hipStream_t stream) {
  const float* raw_res = (const float*)d_in[0];
  const float* rel_res = (const float*)d_in[1];
  const float* raw_g   = (const float*)d_in[2];
  const float* spec_g  = (const float*)d_in[3];
  const float* rel_g   = (const float*)d_in[4];
  const float* gamma   = (const float*)d_in[5];
  const float* beta    = (const float*)d_in[6];
  const float* w1      = (const float*)d_in[7];
  const float* b1      = (const float*)d_in[8];
  const float* w2      = (const float*)d_in[9];
  const float* b2      = (const float*)d_in[10];

  float* out = (float*)d_out;
  // Scratch lives inside d_out's main region; K4 overwrites it afterwards.
  //   gnT:       out[0 .. 98303]            (3072*32 floats)
  //   pre_alpha: out[120000 .. 120031]
  //   partials:  out[131072 .. 2228223]     (128*16*1024 floats)
  //   alpha:     out[67108864 .. 67108895]  (the real alpha output slot)
  float* gnT       = out;
  float* pre_alpha = out + 120000;
  float* partials  = out + 131072;
  float* alpha     = out + (size_t)B_ * T_ * D_;   // 67108864

  ln_kernel<<<dim3(B_), dim3(256), 0, stream>>>(raw_g, spec_g, rel_g, gamma, beta,
                                                gnT, pre_alpha);
  gate_gemm<<<dim3(16, 16), dim3(512), 0, stream>>>(gnT, w1, partials);
  gate_finish<<<dim3(4, B_), dim3(256), 0, stream>>>(partials, b1, w2, pre_alpha);
  alphify<<<dim3(1), dim3(64), 0, stream>>>(pre_alpha, b2, alpha);
  fuse_kernel<<<dim3(512, B_), dim3(256), 0, stream>>>(
      (const float4*)raw_res, (const float4*)rel_res, alpha, d_out ? (float*)d_out : nullptr);
}